// Round 1
// baseline (69.040 us; speedup 1.0000x reference)
//
#include <hip/hip_runtime.h>
#include <hip/hip_bf16.h>

#define BATCHN 16
#define SEQ 4096
#define HIDDEN 128
#define STATE 256
#define MTOT (BATCHN*SEQ)    // 65536
#define NCHUNK 64
#define LCHUNK 64            // SEQ / NCHUNK

typedef __bf16 bf16;
typedef __bf16 bf16x4 __attribute__((ext_vector_type(4)));
typedef __bf16 bf16x8 __attribute__((ext_vector_type(8)));
typedef float f32x4 __attribute__((ext_vector_type(4)));

// ---------------- setup: bf16 copies of B, C + per-state scan params ----------------
__global__ __launch_bounds__(256) void setup_k(const float* __restrict__ A_diag,
        const float* __restrict__ steps, const float* __restrict__ Bm,
        const float* __restrict__ Cm, bf16* __restrict__ Bbf, bf16* __restrict__ Cbf,
        float* __restrict__ prm) {
    int idx = blockIdx.x * 256 + threadIdx.x;   // grid 128 -> 32768
    if (idx < STATE * HIDDEN) {
        Bbf[idx] = (bf16)Bm[idx];
        Cbf[idx] = (bf16)Cm[idx];
    }
    if (blockIdx.x == 0) {
        int n = threadIdx.x;   // 0..255
        float st = 1.0f / (1.0f + expf(-steps[n]));
        float A  = fmaxf(A_diag[n], 0.0f);
        float s2A = st * st * A;
        float schur = 1.0f / (1.0f + s2A);
        float m11 = 1.0f - s2A * schur;
        float m12 = -st * A * schur;
        float m21 = st * schur;
        float m22 = schur;
        prm[0*STATE+n] = m11;
        prm[1*STATE+n] = m12;
        prm[2*STATE+n] = m21;
        prm[3*STATE+n] = m22;
        prm[4*STATE+n] = m11 * st;   // c1
        prm[5*STATE+n] = m21 * st;   // c2
    }
}

// ---------------- GEMM1: Bu[m][n] = sum_k x[m][k] * B[n][k]  (bf16 out) ----------------
// block: 256 thr; Mtile=64, full N=256 (wave w -> n in [64w, 64w+64))
__global__ __launch_bounds__(256) void gemm_xB(const float* __restrict__ x,
        const bf16* __restrict__ Bbf, bf16* __restrict__ Bu) {
    __shared__ bf16 lds[64][136];   // pad: stride 272B -> <=2-way bank aliasing
    const int tid = threadIdx.x;
    const int m0 = blockIdx.x * 64;
    #pragma unroll
    for (int p = 0; p < 8; ++p) {
        int flat = p * 256 + tid;          // 0..2047 (64 rows x 32 float4)
        int row = flat >> 5;
        int c4  = flat & 31;
        float4 v = *reinterpret_cast<const float4*>(&x[(size_t)(m0 + row) * HIDDEN + c4 * 4]);
        bf16x4 w = { (bf16)v.x, (bf16)v.y, (bf16)v.z, (bf16)v.w };
        *reinterpret_cast<bf16x4*>(&lds[row][c4 * 4]) = w;
    }
    __syncthreads();
    const int wid = tid >> 6, lane = tid & 63;
    const int lr = lane & 15;
    const int lk = (lane >> 4) * 8;
    const int n0 = wid * 64;
    f32x4 acc[4][4];
    #pragma unroll
    for (int i = 0; i < 4; ++i)
        #pragma unroll
        for (int j = 0; j < 4; ++j) acc[i][j] = f32x4{0.f, 0.f, 0.f, 0.f};
    #pragma unroll
    for (int ks = 0; ks < 4; ++ks) {
        int k = ks * 32 + lk;
        bf16x8 a[4], b[4];
        #pragma unroll
        for (int mf = 0; mf < 4; ++mf)
            a[mf] = *reinterpret_cast<const bf16x8*>(&lds[mf * 16 + lr][k]);
        #pragma unroll
        for (int nf = 0; nf < 4; ++nf)
            b[nf] = *reinterpret_cast<const bf16x8*>(&Bbf[(size_t)(n0 + nf * 16 + lr) * HIDDEN + k]);
        #pragma unroll
        for (int mf = 0; mf < 4; ++mf)
            #pragma unroll
            for (int nf = 0; nf < 4; ++nf)
                acc[mf][nf] = __builtin_amdgcn_mfma_f32_16x16x32_bf16(a[mf], b[nf], acc[mf][nf], 0, 0, 0);
    }
    const int mrow = (lane >> 4) * 4;
    #pragma unroll
    for (int mf = 0; mf < 4; ++mf)
        #pragma unroll
        for (int nf = 0; nf < 4; ++nf)
            #pragma unroll
            for (int r = 0; r < 4; ++r) {
                int m = m0 + mf * 16 + mrow + r;
                int n = n0 + nf * 16 + lr;
                Bu[(size_t)m * STATE + n] = (bf16)acc[mf][nf][r];
            }
}

// ---------------- scan phase A: per-chunk local scan from zero state ----------------
// grid: BATCH*NCHUNK blocks x 256 thr (thread = state n)
__global__ __launch_bounds__(256) void scan_part(const bf16* __restrict__ Bu,
        const float* __restrict__ prm, float* __restrict__ cs) {
    const int n = threadIdx.x;
    const int chunk = blockIdx.x & (NCHUNK - 1);
    const int b = blockIdx.x >> 6;
    const float m11 = prm[n], m12 = prm[STATE + n], m21 = prm[2*STATE + n],
                m22 = prm[3*STATE + n], c1 = prm[4*STATE + n], c2 = prm[5*STATE + n];
    float s1 = 0.f, s2 = 0.f;
    const bf16* p = &Bu[((size_t)(b * SEQ) + chunk * LCHUNK) * STATE + n];
    #pragma unroll 8
    for (int i = 0; i < LCHUNK; ++i) {
        float bu = (float)p[(size_t)i * STATE];
        float ns1 = fmaf(m11, s1, fmaf(m12, s2, c1 * bu));
        float ns2 = fmaf(m21, s1, fmaf(m22, s2, c2 * bu));
        s1 = ns1; s2 = ns2;
    }
    size_t base = ((size_t)(b * NCHUNK + chunk) * 2) * STATE + n;
    cs[base] = s1;
    cs[base + STATE] = s2;
}

// ---------------- scan phase B: cross-chunk combine (M^64 via squaring) ----------------
// grid: BATCH blocks x 256 thr; in-place: slot c becomes EXCLUSIVE prefix (init state of chunk c)
__global__ __launch_bounds__(256) void scan_comb(float* __restrict__ cs,
        const float* __restrict__ prm) {
    const int n = threadIdx.x;
    const int b = blockIdx.x;
    float p11 = prm[n], p12 = prm[STATE + n], p21 = prm[2*STATE + n], p22 = prm[3*STATE + n];
    #pragma unroll
    for (int i = 0; i < 6; ++i) {   // M^(2^6) = M^64
        float q11 = p11 * p11 + p12 * p21;
        float q12 = p11 * p12 + p12 * p22;
        float q21 = p21 * p11 + p22 * p21;
        float q22 = p21 * p12 + p22 * p22;
        p11 = q11; p12 = q12; p21 = q21; p22 = q22;
    }
    float S1 = 0.f, S2 = 0.f;
    #pragma unroll 8
    for (int c = 0; c < NCHUNK; ++c) {
        size_t base = ((size_t)(b * NCHUNK + c) * 2) * STATE + n;
        float q1 = cs[base], q2 = cs[base + STATE];
        cs[base] = S1; cs[base + STATE] = S2;
        float n1 = fmaf(p11, S1, fmaf(p12, S2, q1));
        float n2 = fmaf(p21, S1, fmaf(p22, S2, q2));
        S1 = n1; S2 = n2;
    }
}

// ---------------- scan phase C: replay with true init state, write y over Bu ----------------
__global__ __launch_bounds__(256) void scan_final(bf16* __restrict__ Bu,
        const float* __restrict__ prm, const float* __restrict__ cs) {
    const int n = threadIdx.x;
    const int chunk = blockIdx.x & (NCHUNK - 1);
    const int b = blockIdx.x >> 6;
    const float m11 = prm[n], m12 = prm[STATE + n], m21 = prm[2*STATE + n],
                m22 = prm[3*STATE + n], c1 = prm[4*STATE + n], c2 = prm[5*STATE + n];
    size_t cbase = ((size_t)(b * NCHUNK + chunk) * 2) * STATE + n;
    float s1 = cs[cbase], s2 = cs[cbase + STATE];
    bf16* p = &Bu[((size_t)(b * SEQ) + chunk * LCHUNK) * STATE + n];
    #pragma unroll 8
    for (int i = 0; i < LCHUNK; ++i) {
        float bu = (float)p[(size_t)i * STATE];
        float ns1 = fmaf(m11, s1, fmaf(m12, s2, c1 * bu));
        float ns2 = fmaf(m21, s1, fmaf(m22, s2, c2 * bu));
        s1 = ns1; s2 = ns2;
        p[(size_t)i * STATE] = (bf16)s2;   // y in place
    }
}

// ---------------- GEMM3: out[m][h] = sum_n y[m][n]*C[h][n] + D[h]*x[m][h] ----------------
// block: 256 thr; Mtile=64, full H=128 (wave w -> h in [32w, 32w+32))
__global__ __launch_bounds__(256) void gemm_yC(const bf16* __restrict__ y,
        const bf16* __restrict__ Cbf, const float* __restrict__ x,
        const float* __restrict__ Dv, float* __restrict__ out) {
    __shared__ bf16 lds[64][264];   // stride 528B -> <=2-way aliasing
    const int tid = threadIdx.x;
    const int m0 = blockIdx.x * 64;
    #pragma unroll
    for (int p = 0; p < 8; ++p) {
        int flat = p * 256 + tid;          // 64 rows x 32 chunks of 8 bf16
        int row = flat >> 5;
        int c8  = flat & 31;
        bf16x8 v = *reinterpret_cast<const bf16x8*>(&y[(size_t)(m0 + row) * STATE + c8 * 8]);
        *reinterpret_cast<bf16x8*>(&lds[row][c8 * 8]) = v;
    }
    __syncthreads();
    const int wid = tid >> 6, lane = tid & 63;
    const int lr = lane & 15;
    const int lk = (lane >> 4) * 8;
    const int h0 = wid * 32;
    f32x4 acc[4][2];
    #pragma unroll
    for (int i = 0; i < 4; ++i) {
        acc[i][0] = f32x4{0.f, 0.f, 0.f, 0.f};
        acc[i][1] = f32x4{0.f, 0.f, 0.f, 0.f};
    }
    #pragma unroll
    for (int ks = 0; ks < 8; ++ks) {
        int k = ks * 32 + lk;
        bf16x8 a[4], bb[2];
        #pragma unroll
        for (int mf = 0; mf < 4; ++mf)
            a[mf] = *reinterpret_cast<const bf16x8*>(&lds[mf * 16 + lr][k]);
        #pragma unroll
        for (int hf = 0; hf < 2; ++hf)
            bb[hf] = *reinterpret_cast<const bf16x8*>(&Cbf[(size_t)(h0 + hf * 16 + lr) * STATE + k]);
        #pragma unroll
        for (int mf = 0; mf < 4; ++mf)
            #pragma unroll
            for (int hf = 0; hf < 2; ++hf)
                acc[mf][hf] = __builtin_amdgcn_mfma_f32_16x16x32_bf16(a[mf], bb[hf], acc[mf][hf], 0, 0, 0);
    }
    const int mrow = (lane >> 4) * 4;
    #pragma unroll
    for (int mf = 0; mf < 4; ++mf)
        #pragma unroll
        for (int hf = 0; hf < 2; ++hf) {
            int h = h0 + hf * 16 + lr;
            float d = Dv[h];
            #pragma unroll
            for (int r = 0; r < 4; ++r) {
                int m = m0 + mf * 16 + mrow + r;
                out[(size_t)m * HIDDEN + h] = acc[mf][hf][r] + d * x[(size_t)m * HIDDEN + h];
            }
        }
}

extern "C" void kernel_launch(void* const* d_in, const int* in_sizes, int n_in,
                              void* d_out, int out_size, void* d_ws, size_t ws_size,
                              hipStream_t stream) {
    const float* x      = (const float*)d_in[0];
    const float* A_diag = (const float*)d_in[1];
    const float* steps  = (const float*)d_in[2];
    const float* Bm     = (const float*)d_in[3];
    const float* Cm     = (const float*)d_in[4];
    const float* Dv     = (const float*)d_in[5];
    float* out = (float*)d_out;

    char* ws = (char*)d_ws;
    const size_t BU_BYTES = (size_t)MTOT * STATE * 2;        // 32 MB (bf16)
    const size_t CS_BYTES = (size_t)BATCHN * NCHUNK * 2 * STATE * 4;  // 2 MB
    bf16*  Bu  = (bf16*)ws;
    float* cs  = (float*)(ws + BU_BYTES);
    bf16*  Bbf = (bf16*)(ws + BU_BYTES + CS_BYTES);
    bf16*  Cbf = (bf16*)(ws + BU_BYTES + CS_BYTES + (size_t)STATE * HIDDEN * 2);
    float* prm = (float*)(ws + BU_BYTES + CS_BYTES + (size_t)STATE * HIDDEN * 4);

    hipLaunchKernelGGL(setup_k, dim3(128), dim3(256), 0, stream, A_diag, steps, Bm, Cm, Bbf, Cbf, prm);
    hipLaunchKernelGGL(gemm_xB, dim3(MTOT / 64), dim3(256), 0, stream, x, Bbf, Bu);
    hipLaunchKernelGGL(scan_part, dim3(BATCHN * NCHUNK), dim3(256), 0, stream, Bu, prm, cs);
    hipLaunchKernelGGL(scan_comb, dim3(BATCHN), dim3(256), 0, stream, cs, prm);
    hipLaunchKernelGGL(scan_final, dim3(BATCHN * NCHUNK), dim3(256), 0, stream, Bu, prm, cs);
    hipLaunchKernelGGL(gemm_yC, dim3(MTOT / 64), dim3(256), 0, stream, Bu, Cbf, x, Dv, out);
}

// Round 2
// 56.926 us; speedup vs baseline: 1.2128x; 1.2128x over previous
//
#include <hip/hip_runtime.h>
#include <hip/hip_bf16.h>

#define BATCHN 16
#define SEQ 4096
#define HIDDEN 128
#define STATE 256
#define MTOT (BATCHN*SEQ)    // 65536
#define NCHUNK 64
#define LCHUNK 64            // SEQ / NCHUNK

typedef __bf16 bf16;
typedef __bf16 bf16x4 __attribute__((ext_vector_type(4)));
typedef __bf16 bf16x8 __attribute__((ext_vector_type(8)));
typedef float f32x4 __attribute__((ext_vector_type(4)));

// ---------------- setup: bf16 copies of B, C + per-state scan params ----------------
__global__ __launch_bounds__(256) void setup_k(const float* __restrict__ A_diag,
        const float* __restrict__ steps, const float* __restrict__ Bm,
        const float* __restrict__ Cm, bf16* __restrict__ Bbf, bf16* __restrict__ Cbf,
        float* __restrict__ prm) {
    int idx = blockIdx.x * 256 + threadIdx.x;   // grid 128 -> 32768
    if (idx < STATE * HIDDEN) {
        Bbf[idx] = (bf16)Bm[idx];
        Cbf[idx] = (bf16)Cm[idx];
    }
    if (blockIdx.x == 0) {
        int n = threadIdx.x;   // 0..255
        float st = 1.0f / (1.0f + expf(-steps[n]));
        float A  = fmaxf(A_diag[n], 0.0f);
        float s2A = st * st * A;
        float schur = 1.0f / (1.0f + s2A);
        float m11 = 1.0f - s2A * schur;
        float m12 = -st * A * schur;
        float m21 = st * schur;
        float m22 = schur;
        prm[0*STATE+n] = m11;
        prm[1*STATE+n] = m12;
        prm[2*STATE+n] = m21;
        prm[3*STATE+n] = m22;
        prm[4*STATE+n] = m11 * st;   // c1
        prm[5*STATE+n] = m21 * st;   // c2
    }
}

// Shared device helper: stage x tile (fp32->bf16) into xl
__device__ __forceinline__ void stage_x(const float* __restrict__ x, int m0, int tid,
                                        bf16 (*xl)[136]) {
    #pragma unroll
    for (int p = 0; p < 8; ++p) {
        int flat = p * 256 + tid;          // 0..2047 (64 rows x 32 float4)
        int row = flat >> 5;
        int c4  = flat & 31;
        float4 v = *reinterpret_cast<const float4*>(&x[(size_t)(m0 + row) * HIDDEN + c4 * 4]);
        bf16x4 w = { (bf16)v.x, (bf16)v.y, (bf16)v.z, (bf16)v.w };
        *reinterpret_cast<bf16x4*>(&xl[row][c4 * 4]) = w;
    }
}

// Shared device helper: GEMM1 tile -> write Bu into bu LDS (bf16)
__device__ __forceinline__ void gemm1_to_lds(const bf16 (*xl)[136],
        const bf16* __restrict__ Bbf, int tid, bf16 (*bu)[264]) {
    const int wid = tid >> 6, lane = tid & 63;
    const int lr = lane & 15;
    const int lk = (lane >> 4) * 8;
    const int n0 = wid * 64;
    f32x4 acc[4][4];
    #pragma unroll
    for (int i = 0; i < 4; ++i)
        #pragma unroll
        for (int j = 0; j < 4; ++j) acc[i][j] = f32x4{0.f, 0.f, 0.f, 0.f};
    #pragma unroll
    for (int ks = 0; ks < 4; ++ks) {
        int k = ks * 32 + lk;
        bf16x8 a[4], b[4];
        #pragma unroll
        for (int mf = 0; mf < 4; ++mf)
            a[mf] = *reinterpret_cast<const bf16x8*>(&xl[mf * 16 + lr][k]);
        #pragma unroll
        for (int nf = 0; nf < 4; ++nf)
            b[nf] = *reinterpret_cast<const bf16x8*>(&Bbf[(size_t)(n0 + nf * 16 + lr) * HIDDEN + k]);
        #pragma unroll
        for (int mf = 0; mf < 4; ++mf)
            #pragma unroll
            for (int nf = 0; nf < 4; ++nf)
                acc[mf][nf] = __builtin_amdgcn_mfma_f32_16x16x32_bf16(a[mf], b[nf], acc[mf][nf], 0, 0, 0);
    }
    const int mrow = (lane >> 4) * 4;
    #pragma unroll
    for (int mf = 0; mf < 4; ++mf)
        #pragma unroll
        for (int nf = 0; nf < 4; ++nf)
            #pragma unroll
            for (int r = 0; r < 4; ++r)
                bu[mf * 16 + mrow + r][n0 + nf * 16 + lr] = (bf16)acc[mf][nf][r];
}

// ---------------- K1: GEMM1 + local chunk scan (phase A) -> cs only ----------------
__global__ __launch_bounds__(256) void k1_gemm_scanA(const float* __restrict__ x,
        const bf16* __restrict__ Bbf, const float* __restrict__ prm,
        float* __restrict__ cs) {
    __shared__ bf16 xl[64][136];
    __shared__ bf16 bu[64][264];
    const int tid = threadIdx.x;
    const int m0 = blockIdx.x * 64;
    stage_x(x, m0, tid, xl);
    __syncthreads();
    gemm1_to_lds(xl, Bbf, tid, bu);
    __syncthreads();
    // local scan over the 64 timesteps, thread = state n
    const int n = tid;
    const float m11 = prm[n], m12 = prm[STATE + n], m21 = prm[2*STATE + n],
                m22 = prm[3*STATE + n], c1 = prm[4*STATE + n], c2 = prm[5*STATE + n];
    float s1 = 0.f, s2 = 0.f;
    #pragma unroll 8
    for (int t = 0; t < LCHUNK; ++t) {
        float v = (float)bu[t][n];
        float ns1 = fmaf(m11, s1, fmaf(m12, s2, c1 * v));
        float ns2 = fmaf(m21, s1, fmaf(m22, s2, c2 * v));
        s1 = ns1; s2 = ns2;
    }
    const int b = m0 >> 12;            // /SEQ
    const int chunk = (m0 >> 6) & (NCHUNK - 1);
    size_t base = ((size_t)(b * NCHUNK + chunk) * 2) * STATE + n;
    cs[base] = s1;
    cs[base + STATE] = s2;
}

// ---------------- phase B: cross-chunk combine (M^64 via squaring) ----------------
__global__ __launch_bounds__(256) void scan_comb(float* __restrict__ cs,
        const float* __restrict__ prm) {
    const int n = threadIdx.x;
    const int b = blockIdx.x;
    float p11 = prm[n], p12 = prm[STATE + n], p21 = prm[2*STATE + n], p22 = prm[3*STATE + n];
    #pragma unroll
    for (int i = 0; i < 6; ++i) {   // M^(2^6) = M^64
        float q11 = p11 * p11 + p12 * p21;
        float q12 = p11 * p12 + p12 * p22;
        float q21 = p21 * p11 + p22 * p21;
        float q22 = p21 * p12 + p22 * p22;
        p11 = q11; p12 = q12; p21 = q21; p22 = q22;
    }
    float S1 = 0.f, S2 = 0.f;
    #pragma unroll 8
    for (int c = 0; c < NCHUNK; ++c) {
        size_t base = ((size_t)(b * NCHUNK + c) * 2) * STATE + n;
        float q1 = cs[base], q2 = cs[base + STATE];
        cs[base] = S1; cs[base + STATE] = S2;
        float n1 = fmaf(p11, S1, fmaf(p12, S2, q1));
        float n2 = fmaf(p21, S1, fmaf(p22, S2, q2));
        S1 = n1; S2 = n2;
    }
}

// ---------------- K2: GEMM1 (recompute) + phase-C scan + GEMM2 + D*x ----------------
__global__ __launch_bounds__(256) void k2_gemm_scan_gemm(const float* __restrict__ x,
        const bf16* __restrict__ Bbf, const bf16* __restrict__ Cbf,
        const float* __restrict__ prm, const float* __restrict__ cs,
        const float* __restrict__ Dv, float* __restrict__ out) {
    __shared__ bf16 xl[64][136];
    __shared__ bf16 bu[64][264];
    const int tid = threadIdx.x;
    const int m0 = blockIdx.x * 64;
    stage_x(x, m0, tid, xl);
    __syncthreads();
    gemm1_to_lds(xl, Bbf, tid, bu);
    __syncthreads();
    // phase-C scan with true init state; overwrite bu with y = s2 (bf16)
    {
        const int n = tid;
        const float m11 = prm[n], m12 = prm[STATE + n], m21 = prm[2*STATE + n],
                    m22 = prm[3*STATE + n], c1 = prm[4*STATE + n], c2 = prm[5*STATE + n];
        const int b = m0 >> 12;
        const int chunk = (m0 >> 6) & (NCHUNK - 1);
        size_t cbase = ((size_t)(b * NCHUNK + chunk) * 2) * STATE + n;
        float s1 = cs[cbase], s2 = cs[cbase + STATE];
        #pragma unroll 8
        for (int t = 0; t < LCHUNK; ++t) {
            float v = (float)bu[t][n];
            float ns1 = fmaf(m11, s1, fmaf(m12, s2, c1 * v));
            float ns2 = fmaf(m21, s1, fmaf(m22, s2, c2 * v));
            s1 = ns1; s2 = ns2;
            bu[t][n] = (bf16)s2;      // y in LDS
        }
    }
    __syncthreads();
    // GEMM2: out[m][h] = sum_n y[m][n]*C[h][n] + D[h]*x[m][h]
    const int wid = tid >> 6, lane = tid & 63;
    const int lr = lane & 15;
    const int lk = (lane >> 4) * 8;
    const int h0 = wid * 32;
    f32x4 acc2[4][2];
    #pragma unroll
    for (int i = 0; i < 4; ++i) {
        acc2[i][0] = f32x4{0.f, 0.f, 0.f, 0.f};
        acc2[i][1] = f32x4{0.f, 0.f, 0.f, 0.f};
    }
    #pragma unroll
    for (int ks = 0; ks < 8; ++ks) {
        int k = ks * 32 + lk;
        bf16x8 a[4], bb[2];
        #pragma unroll
        for (int mf = 0; mf < 4; ++mf)
            a[mf] = *reinterpret_cast<const bf16x8*>(&bu[mf * 16 + lr][k]);
        #pragma unroll
        for (int hf = 0; hf < 2; ++hf)
            bb[hf] = *reinterpret_cast<const bf16x8*>(&Cbf[(size_t)(h0 + hf * 16 + lr) * STATE + k]);
        #pragma unroll
        for (int mf = 0; mf < 4; ++mf)
            #pragma unroll
            for (int hf = 0; hf < 2; ++hf)
                acc2[mf][hf] = __builtin_amdgcn_mfma_f32_16x16x32_bf16(a[mf], bb[hf], acc2[mf][hf], 0, 0, 0);
    }
    const int mrow = (lane >> 4) * 4;
    #pragma unroll
    for (int mf = 0; mf < 4; ++mf)
        #pragma unroll
        for (int hf = 0; hf < 2; ++hf) {
            int h = h0 + hf * 16 + lr;
            float d = Dv[h];
            #pragma unroll
            for (int r = 0; r < 4; ++r) {
                int ml = mf * 16 + mrow + r;
                out[(size_t)(m0 + ml) * HIDDEN + h] = acc2[mf][hf][r] + d * (float)xl[ml][h];
            }
        }
}

extern "C" void kernel_launch(void* const* d_in, const int* in_sizes, int n_in,
                              void* d_out, int out_size, void* d_ws, size_t ws_size,
                              hipStream_t stream) {
    const float* x      = (const float*)d_in[0];
    const float* A_diag = (const float*)d_in[1];
    const float* steps  = (const float*)d_in[2];
    const float* Bm     = (const float*)d_in[3];
    const float* Cm     = (const float*)d_in[4];
    const float* Dv     = (const float*)d_in[5];
    float* out = (float*)d_out;

    char* ws = (char*)d_ws;
    const size_t CS_BYTES = (size_t)BATCHN * NCHUNK * 2 * STATE * 4;  // 2 MB
    float* cs  = (float*)ws;
    bf16*  Bbf = (bf16*)(ws + CS_BYTES);
    bf16*  Cbf = (bf16*)(ws + CS_BYTES + (size_t)STATE * HIDDEN * 2);
    float* prm = (float*)(ws + CS_BYTES + (size_t)STATE * HIDDEN * 4);

    hipLaunchKernelGGL(setup_k, dim3(128), dim3(256), 0, stream, A_diag, steps, Bm, Cm, Bbf, Cbf, prm);
    hipLaunchKernelGGL(k1_gemm_scanA, dim3(MTOT / 64), dim3(256), 0, stream, x, Bbf, prm, cs);
    hipLaunchKernelGGL(scan_comb, dim3(BATCHN), dim3(256), 0, stream, cs, prm);
    hipLaunchKernelGGL(k2_gemm_scan_gemm, dim3(MTOT / 64), dim3(256), 0, stream,
                       x, Bbf, Cbf, prm, cs, Dv, out);
}